// Round 2
// baseline (168.294 us; speedup 1.0000x reference)
//
#include <hip/hip_runtime.h>

// HBilinearUpsample: Poincare-ball geodesic-midpoint 2x upsample.
// midpoint(x,y) = A*x + B*y with scalars A,B from (|x|^2,|y|^2,x.y) only:
//   w = mobius(-x,y) = (-alpha*x + beta*y)/den_w,
//     alpha = 1-2xy+y2, beta = 1-x2, den_w = 1-2xy+x2*y2
//   tanh(0.5*atanh(r)) = r/(1+sqrt(1-r^2))   (lam cancels exactly, c=1)
//   second = t*w, t = s/wn, s = a/(1+sqrt(1-a^2)), a = min(wn, 1-1e-5)
//   mid = [(1+2xs+s2)*x + beta*second]/den
// Center of 2x2 cell = midpoint(midpoint(x00,x10), midpoint(x01,x11)) --
// still a linear combo of the 4 corners, coefficients from the 4x4 Gram.
// Edge replication == clamped neighbor (mid(x,x)=x exactly).
//
// R1: block = (128 w, 4 channel-slices) = 512 thr; Gram reduced via LDS.
// 8 waves/block x 4 blocks/CU = 32 waves/CU (was 8) -> hide load latency.

#define EPSF   1e-15f
#define MAXAT  0.99999f

__device__ __forceinline__ void midcoef(float x2, float y2, float xy,
                                        float& A, float& B) {
    float alpha  = 1.0f - 2.0f * xy + y2;
    float beta   = 1.0f - x2;
    float den_w  = fmaxf(1.0f - 2.0f * xy + x2 * y2, EPSF);
    float inv_dw = 1.0f / den_w;
    float dxw = (beta * xy - alpha * x2) * inv_dw;          // dot(x,w)
    float wn2 = (alpha * alpha * x2 - 2.0f * alpha * beta * xy + beta * beta * y2)
                * inv_dw * inv_dw;                          // |w|^2
    wn2 = fmaxf(wn2, EPSF);
    float wn = sqrtf(wn2);
    float a  = fminf(wn, MAXAT);
    float s  = a / (1.0f + sqrtf(fmaxf(1.0f - a * a, 0.0f)));
    float t  = s / wn;                 // second = t * w
    float xs = t * dxw;                // dot(x, second)
    float s2 = t * t * wn2;            // |second|^2
    float den     = fmaxf(1.0f + 2.0f * xs + x2 * s2, EPSF);
    float inv_den = 1.0f / den;
    float k = beta * t * inv_dw;
    A = ((1.0f + 2.0f * xs + s2) - k * alpha) * inv_den;
    B = (k * beta) * inv_den;
}

__global__ __launch_bounds__(512)
void hupsample_kernel(const float* __restrict__ x, float* __restrict__ out) {
    constexpr int C = 64, H = 128, W = 128;
    constexpr int CS = H * W;            // channel stride (elems)
    constexpr int CPS = C / 4;           // channels per slice = 16

    __shared__ float part[4][128][11];   // [slice][w][10 dots], pad 11
    __shared__ float coef[128][9];       // [w][8 coefs], pad 9

    const int w  = threadIdx.x;          // 0..127
    const int s  = threadIdx.y;          // 0..3 (channel slice)
    const int h  = blockIdx.x;           // 0..127
    const int b  = blockIdx.y;           // 0..7
    const int wp = (w + 1 < W) ? (w + 1) : (W - 1);
    const int hp = (h + 1 < H) ? (h + 1) : (H - 1);

    const float* xb  = x + (size_t)b * C * CS + (size_t)(s * CPS) * CS;
    const float* p00 = xb + h  * W + w;
    const float* p10 = xb + h  * W + wp;
    const float* p01 = xb + hp * W + w;
    const float* p11 = xb + hp * W + wp;

    // ---- pass 1: partial Gram over this slice's 16 channels ----
    float g00 = 0.f, g10 = 0.f, g01 = 0.f, g11 = 0.f;
    float d0010 = 0.f, d0111 = 0.f, d0001 = 0.f;
    float d0011 = 0.f, d1001 = 0.f, d1011 = 0.f;
#pragma unroll 4
    for (int c = 0; c < CPS; ++c) {
        float v00 = p00[c * CS];
        float v10 = p10[c * CS];
        float v01 = p01[c * CS];
        float v11 = p11[c * CS];
        g00   += v00 * v00;  g10   += v10 * v10;
        g01   += v01 * v01;  g11   += v11 * v11;
        d0010 += v00 * v10;  d0111 += v01 * v11;
        d0001 += v00 * v01;  d0011 += v00 * v11;
        d1001 += v10 * v01;  d1011 += v10 * v11;
    }
    part[s][w][0] = g00;   part[s][w][1] = g10;
    part[s][w][2] = g01;   part[s][w][3] = g11;
    part[s][w][4] = d0010; part[s][w][5] = d0111;
    part[s][w][6] = d0001; part[s][w][7] = d0011;
    part[s][w][8] = d1001; part[s][w][9] = d1011;
    __syncthreads();

    // ---- slice 0 reduces + computes the 8 coefficients ----
    if (s == 0) {
        float t0[10];
#pragma unroll
        for (int k = 0; k < 10; ++k)
            t0[k] = part[0][w][k] + part[1][w][k] + part[2][w][k] + part[3][w][k];
        float G00 = t0[0], G10 = t0[1], G01 = t0[2], G11 = t0[3];
        float D0010 = t0[4], D0111 = t0[5], D0001 = t0[6];
        float D0011 = t0[7], D1001 = t0[8], D1011 = t0[9];

        float Ah, Bh;  midcoef(G00, G10, D0010, Ah, Bh);   // horiz mid, row h
        float A2, B2;  midcoef(G01, G11, D0111, A2, B2);   // horiz mid, row h+1
        float Av, Bv;  midcoef(G00, G01, D0001, Av, Bv);   // vert mid

        float a2 = Ah * Ah * G00 + 2.0f * Ah * Bh * D0010 + Bh * Bh * G10;
        float b2 = A2 * A2 * G01 + 2.0f * A2 * B2 * D0111 + B2 * B2 * G11;
        float ab = Ah * A2 * D0001 + Ah * B2 * D0011
                 + Bh * A2 * D1001 + Bh * B2 * D1011;
        float A3, B3;  midcoef(a2, b2, ab, A3, B3);

        coef[w][0] = Ah;      coef[w][1] = Bh;
        coef[w][2] = Av;      coef[w][3] = Bv;
        coef[w][4] = A3 * Ah; coef[w][5] = A3 * Bh;
        coef[w][6] = B3 * A2; coef[w][7] = B3 * B2;
    }
    __syncthreads();

    const float Ah = coef[w][0], Bh = coef[w][1];
    const float Av = coef[w][2], Bv = coef[w][3];
    const float CA = coef[w][4], CB = coef[w][5];
    const float CC = coef[w][6], CD = coef[w][7];

    // ---- pass 2: emit this slice's 16 channels of the 2x2 output cell ----
    float* ob = out + (size_t)b * C * (4 * CS) + (size_t)(s * CPS) * (4 * CS);
    const size_t rbase = (size_t)(2 * h) * (2 * W) + (size_t)(2 * w);
#pragma unroll 4
    for (int c = 0; c < CPS; ++c) {
        float v00 = p00[c * CS];
        float v10 = p10[c * CS];
        float v01 = p01[c * CS];
        float v11 = p11[c * CS];
        float oh = Ah * v00 + Bh * v10;
        float ov = Av * v00 + Bv * v01;
        float oc = CA * v00 + CB * v10 + CC * v01 + CD * v11;
        size_t base = (size_t)c * (4 * CS) + rbase;
        *(float2*)(ob + base)         = make_float2(v00, oh);
        *(float2*)(ob + base + 2 * W) = make_float2(ov, oc);
    }
}

extern "C" void kernel_launch(void* const* d_in, const int* in_sizes, int n_in,
                              void* d_out, int out_size, void* d_ws, size_t ws_size,
                              hipStream_t stream) {
    const float* x = (const float*)d_in[0];
    float* out = (float*)d_out;
    dim3 grid(128, 8);      // (h, b)
    dim3 block(128, 4);     // (w, channel slice)
    hipLaunchKernelGGL(hupsample_kernel, grid, block, 0, stream, x, out);
}

// Round 3
// 167.262 us; speedup vs baseline: 1.0062x; 1.0062x over previous
//
#include <hip/hip_runtime.h>

// HBilinearUpsample: Poincare-ball geodesic-midpoint 2x upsample.
// midpoint(x,y) = A*x + B*y with scalars A,B from (|x|^2,|y|^2,x.y) only
// (c=1; lam cancels; tanh(0.5*atanh(r)) = r/(1+sqrt(1-r^2))).
// Center of 2x2 cell = midpoint(midpoint(x00,x10), midpoint(x01,x11)) --
// a linear combo of the 4 corners, coefficients from the 4x4 Gram matrix.
// Edge replication == clamped neighbor (mid(x,x)=x exactly).
//
// R2: two kernels. A: per-cell Gram reduce -> 8 SoA coefficient maps in d_ws
// (4.2 MB). B: streaming apply, one thread per (cell, 4-channel group),
// 32768 waves, coalesced coef loads reused 4x, float2 stores. Decouples the
// serial reduce->apply structure that R1's occupancy bump couldn't fix.

#define EPSF   1e-15f
#define MAXAT  0.99999f

__device__ __forceinline__ void midcoef(float x2, float y2, float xy,
                                        float& A, float& B) {
    float alpha  = 1.0f - 2.0f * xy + y2;
    float beta   = 1.0f - x2;
    float den_w  = fmaxf(1.0f - 2.0f * xy + x2 * y2, EPSF);
    float inv_dw = 1.0f / den_w;
    float dxw = (beta * xy - alpha * x2) * inv_dw;          // dot(x,w)
    float wn2 = (alpha * alpha * x2 - 2.0f * alpha * beta * xy + beta * beta * y2)
                * inv_dw * inv_dw;                          // |w|^2
    wn2 = fmaxf(wn2, EPSF);
    float wn = sqrtf(wn2);
    float a  = fminf(wn, MAXAT);
    float s  = a / (1.0f + sqrtf(fmaxf(1.0f - a * a, 0.0f)));
    float t  = s / wn;                 // second = t * w
    float xs = t * dxw;                // dot(x, second)
    float s2 = t * t * wn2;            // |second|^2
    float den     = fmaxf(1.0f + 2.0f * xs + x2 * s2, EPSF);
    float inv_den = 1.0f / den;
    float k = beta * t * inv_dw;
    A = ((1.0f + 2.0f * xs + s2) - k * alpha) * inv_den;
    B = (k * beta) * inv_den;
}

constexpr int Cc = 64, Hc = 128, Wc = 128;
constexpr int CSc = Hc * Wc;                 // channel stride
constexpr int NCELL = 8 * Hc * Wc;           // 131072 cells (b,h,w)

// ---------------- Kernel A: coefficient maps ----------------
__global__ __launch_bounds__(512)
void coef_kernel(const float* __restrict__ x, float* __restrict__ cof) {
    constexpr int CPS = Cc / 4;              // 16 channels per slice
    __shared__ float part[4][128][11];       // [slice][w][10 dots], pad 11

    const int w  = threadIdx.x;              // 0..127
    const int s  = threadIdx.y;              // 0..3
    const int h  = blockIdx.x;               // 0..127
    const int b  = blockIdx.y;               // 0..7
    const int wp = (w + 1 < Wc) ? (w + 1) : (Wc - 1);
    const int hp = (h + 1 < Hc) ? (h + 1) : (Hc - 1);

    const float* xb  = x + (size_t)b * Cc * CSc + (size_t)(s * CPS) * CSc;
    const float* p00 = xb + h  * Wc + w;
    const float* p10 = xb + h  * Wc + wp;
    const float* p01 = xb + hp * Wc + w;
    const float* p11 = xb + hp * Wc + wp;

    float g00 = 0.f, g10 = 0.f, g01 = 0.f, g11 = 0.f;
    float d0010 = 0.f, d0111 = 0.f, d0001 = 0.f;
    float d0011 = 0.f, d1001 = 0.f, d1011 = 0.f;
#pragma unroll 4
    for (int c = 0; c < CPS; ++c) {
        float v00 = p00[c * CSc];
        float v10 = p10[c * CSc];
        float v01 = p01[c * CSc];
        float v11 = p11[c * CSc];
        g00   += v00 * v00;  g10   += v10 * v10;
        g01   += v01 * v01;  g11   += v11 * v11;
        d0010 += v00 * v10;  d0111 += v01 * v11;
        d0001 += v00 * v01;  d0011 += v00 * v11;
        d1001 += v10 * v01;  d1011 += v10 * v11;
    }
    part[s][w][0] = g00;   part[s][w][1] = g10;
    part[s][w][2] = g01;   part[s][w][3] = g11;
    part[s][w][4] = d0010; part[s][w][5] = d0111;
    part[s][w][6] = d0001; part[s][w][7] = d0011;
    part[s][w][8] = d1001; part[s][w][9] = d1011;
    __syncthreads();

    if (s == 0) {
        float t0[10];
#pragma unroll
        for (int k = 0; k < 10; ++k)
            t0[k] = part[0][w][k] + part[1][w][k] + part[2][w][k] + part[3][w][k];
        float G00 = t0[0], G10 = t0[1], G01 = t0[2], G11 = t0[3];
        float D0010 = t0[4], D0111 = t0[5], D0001 = t0[6];
        float D0011 = t0[7], D1001 = t0[8], D1011 = t0[9];

        float Ah, Bh;  midcoef(G00, G10, D0010, Ah, Bh);   // horiz mid, row h
        float A2, B2;  midcoef(G01, G11, D0111, A2, B2);   // horiz mid, row h+1
        float Av, Bv;  midcoef(G00, G01, D0001, Av, Bv);   // vert mid

        float a2 = Ah * Ah * G00 + 2.0f * Ah * Bh * D0010 + Bh * Bh * G10;
        float b2 = A2 * A2 * G01 + 2.0f * A2 * B2 * D0111 + B2 * B2 * G11;
        float ab = Ah * A2 * D0001 + Ah * B2 * D0011
                 + Bh * A2 * D1001 + Bh * B2 * D1011;
        float A3, B3;  midcoef(a2, b2, ab, A3, B3);

        const size_t ci = (size_t)(b * Hc + h) * Wc + w;   // SoA: cof[k][cell]
        cof[0 * NCELL + ci] = Ah;      cof[1 * NCELL + ci] = Bh;
        cof[2 * NCELL + ci] = Av;      cof[3 * NCELL + ci] = Bv;
        cof[4 * NCELL + ci] = A3 * Ah; cof[5 * NCELL + ci] = A3 * Bh;
        cof[6 * NCELL + ci] = B3 * A2; cof[7 * NCELL + ci] = B3 * B2;
    }
}

// ---------------- Kernel B: streaming apply ----------------
__global__ __launch_bounds__(128)
void apply_kernel(const float* __restrict__ x, const float* __restrict__ cof,
                  float* __restrict__ out) {
    const int w  = threadIdx.x;              // 0..127
    const int h  = blockIdx.x;               // 0..127
    const int cg = blockIdx.y;               // 0..15 (4-channel group)
    const int b  = blockIdx.z;               // 0..7
    const int wp = (w + 1 < Wc) ? (w + 1) : (Wc - 1);
    const int hp = (h + 1 < Hc) ? (h + 1) : (Hc - 1);

    const size_t ci = (size_t)(b * Hc + h) * Wc + w;
    const float Ah = cof[0 * NCELL + ci], Bh = cof[1 * NCELL + ci];
    const float Av = cof[2 * NCELL + ci], Bv = cof[3 * NCELL + ci];
    const float CA = cof[4 * NCELL + ci], CB = cof[5 * NCELL + ci];
    const float CC = cof[6 * NCELL + ci], CD = cof[7 * NCELL + ci];

    const int c0 = cg * 4;
    const float* xc = x + ((size_t)b * Cc + c0) * CSc;
    float* ob = out + ((size_t)b * Cc + c0) * (4 * CSc)
              + (size_t)(2 * h) * (2 * Wc) + (size_t)(2 * w);

#pragma unroll
    for (int c = 0; c < 4; ++c) {
        float v00 = xc[c * CSc + h  * Wc + w];
        float v10 = xc[c * CSc + h  * Wc + wp];
        float v01 = xc[c * CSc + hp * Wc + w];
        float v11 = xc[c * CSc + hp * Wc + wp];
        float oh = Ah * v00 + Bh * v10;
        float ov = Av * v00 + Bv * v01;
        float oc = CA * v00 + CB * v10 + CC * v01 + CD * v11;
        float* o = ob + (size_t)c * (4 * CSc);
        *(float2*)o             = make_float2(v00, oh);
        *(float2*)(o + 2 * Wc)  = make_float2(ov, oc);
    }
}

extern "C" void kernel_launch(void* const* d_in, const int* in_sizes, int n_in,
                              void* d_out, int out_size, void* d_ws, size_t ws_size,
                              hipStream_t stream) {
    const float* x = (const float*)d_in[0];
    float* out = (float*)d_out;
    float* cof = (float*)d_ws;               // 8 * 131072 * 4 B = 4.2 MB

    dim3 gridA(128, 8);                      // (h, b)
    dim3 blockA(128, 4);                     // (w, channel slice)
    hipLaunchKernelGGL(coef_kernel, gridA, blockA, 0, stream, x, cof);

    dim3 gridB(128, 16, 8);                  // (h, channel-group, b)
    dim3 blockB(128);                        // w
    hipLaunchKernelGGL(apply_kernel, gridB, blockB, 0, stream, x, cof, out);
}